// Round 3
// baseline (132.806 us; speedup 1.0000x reference)
//
#include <hip/hip_runtime.h>

#define IMG 65536                  // H*W

typedef _Float16 half8  __attribute__((ext_vector_type(8)));
typedef _Float16 half4v __attribute__((ext_vector_type(4)));
typedef _Float16 half2v __attribute__((ext_vector_type(2)));
typedef float    floatx4 __attribute__((ext_vector_type(4)));

__device__ __forceinline__ float sigm(float x){ return 1.0f/(1.0f + __expf(-x)); }
__device__ __forceinline__ float tanh_fast(float x){
    float t = __expf(2.0f*x);
    return 1.0f - 2.0f/(t + 1.0f);
}
// XOR swizzle to spread 16B-stride LDS accesses across bank groups
__device__ __forceinline__ int swz(int px){ return px ^ ((px >> 3) & 7); }

__global__ void zero_out(float* out){ out[0] = 0.0f; }

__device__ __forceinline__ void row6(const float* __restrict__ u, int rb, int j0, float v[6]){
    const float4 c4 = *(const float4*)&u[rb + j0];
    v[1] = c4.x; v[2] = c4.y; v[3] = c4.z; v[4] = c4.w;
    v[0] = (j0 > 0)   ? u[rb + j0 - 1] : 0.0f;
    v[5] = (j0 < 252) ? u[rb + j0 + 4] : 0.0f;
}
__device__ __forceinline__ void zero6(float v[6]){
    v[0]=v[1]=v[2]=v[3]=v[4]=v[5]=0.0f;
}
__device__ __forceinline__ void stencil4(const float k2[4], const float m1[4],
    const float m2[4], const float hx[4], const float hs[4], const float hy[4],
    const float vc[6], const float vn[6], const float vs[6], float rp[4])
{
    #pragma unroll
    for (int p = 0; p < 4; ++p){
        float hxx = hx[p], hyy = hy[p];
        rp[p] = (k2[p] + 2.0f*(hxx + hyy))*vc[p+1]
              + (0.5f*m1[p] - hxx)*vc[p+2]
              - (0.5f*m1[p] + hxx)*vc[p]
              + (0.5f*m2[p] - hyy)*vn[p+1]
              - (0.5f*m2[p] + hyy)*vs[p+1]
              - 0.25f*hs[p]*(vn[p+2] - vs[p+2] - vn[p] + vs[p]);
    }
}

// ---------------------------------------------------------------------------
// Fully fused: conv(MFMA f16, 16 oc = 8 field ch x 2 t) -> fields in LDS ->
// y = A(x) in LDS (aliases dead x-tile) -> z = A(y) -> residual + reduction.
// Block: (b, t-pair, 2-row strip), 512 threads.
// LDS map (bytes): [0,24768) xt (conv) / ys+red (stencil); [24768,57536) fl.
// fl channels per px (f16 x8): k2, m1, m2, Hxx, Hs, 0, Hyy, D.
// ---------------------------------------------------------------------------
__global__ __launch_bounds__(512) void fused_all(
    const float* __restrict__ x, const float* __restrict__ w,
    float* __restrict__ out)
{
    __shared__ __align__(16) unsigned char smem[24768 + 32768];
    _Float16* xt  = (_Float16*)smem;
    _Float16* fl  = (_Float16*)(smem + 24768);
    float*    ys  = (float*)smem;              // aliases xt (dead after conv)
    float*    red = (float*)(smem + 8576);     // after ys region

    const int tid  = threadIdx.x;
    const int lane = tid & 63;
    const int wv   = tid >> 6;
    const int l16  = lane & 15;
    const int quad = lane >> 4;
    const int i0   = blockIdx.x << 1;          // strip: z rows i0, i0+1
    const int b    = blockIdx.y >> 2;
    const int tp   = blockIdx.y & 3;           // t-pair {2tp, 2tp+1}

    // ---- stage x rows i0-2..i0+3, cols -1..256, 8 ch, f16 interleaved ----
    for (int e = tid; e < 6*4*258; e += 512){
        int cc = e % 258;
        int q  = e / 258;                      // 0..23
        int rr = q >> 2;
        int cp = q & 3;                        // channel pair
        int gi = i0 - 2 + rr, gj = cc - 1;
        float v0 = 0.0f, v1 = 0.0f;
        if ((unsigned)gi < 256u && (unsigned)gj < 256u){
            int base = (((b << 3) + (cp << 1)) << 16) + (gi << 8) + gj;
            v0 = x[base];
            v1 = x[base + IMG];
        }
        half2v h; h[0] = (_Float16)v0; h[1] = (_Float16)v1;
        *(half2v*)&xt[(rr*258 + cc)*8 + (cp << 1)] = h;
    }

    // ---- weights: A[m=l16][k=quad*8+j]; oc = f*8 + (2tp + tl) ----
    half8 afr[3];
    int boff[3];
    {
        int oc = ((l16 & 7) << 3) + (tp << 1) + (l16 >> 3);
        #pragma unroll
        for (int s = 0; s < 3; ++s){
            int tap = s*4 + quad;
            half8 a;
            if (tap < 9){
                #pragma unroll
                for (int j = 0; j < 8; ++j)
                    a[j] = (_Float16)w[(oc*8 + j)*9 + tap];
                int dh = tap/3, dw = tap - dh*3;
                boff[s] = (dh*258 + dw)*8;
            } else {
                #pragma unroll
                for (int j = 0; j < 8; ++j) a[j] = (_Float16)0.0f;
                boff[s] = 0;
            }
            afr[s] = a;
        }
    }
    __syncthreads();

    // ---- conv: 64 tiles (4 rows x 16 colgroups), 8 per wave ----
    float ldacc = 0.0f;
    #pragma unroll
    for (int it = 0; it < 8; ++it){
        int g  = it*8 + wv;
        int ry = g >> 4;                       // field row: gi = i0-1+ry
        int jb = ((g & 15) << 4) + l16;        // px col
        int base = (ry*258 + jb)*8;
        floatx4 acc = {0,0,0,0};
        #pragma unroll
        for (int s = 0; s < 3; ++s){
            half8 bf = *(const half8*)&xt[base + boff[s]];
            acc = __builtin_amdgcn_mfma_f32_16x16x32_f16(afr[s], bf, acc, 0, 0, 0);
        }
        // epilogue: lane holds oc rows m=quad*4+rg for px jb
        int tl    = quad >> 1;
        int flidx = ((((ry << 1) + tl) << 8) + swz(jb)) << 3;
        half4v v;
        if ((quad & 1) == 0){                  // f = 0..3
            float s0 = 0.99f*sigm(acc[0]) + 0.01f;
            v[0] = (_Float16)(s0*s0);          // kappa^2
            v[1] = (_Float16)acc[1];           // m1
            v[2] = (_Float16)acc[2];           // m2
            v[3] = (_Float16)(0.99f*sigm(acc[3]) + 0.01f);   // Hxx
            *(half4v*)&fl[flidx] = v;
        } else {                               // f = 4..7
            float hs  = 0.1f*(tanh_fast(acc[0]) + tanh_fast(acc[1]));
            float hyy = 0.99f*sigm(acc[2]) + 0.01f;
            float tau = 9.9f*sigm(acc[3]) + 0.1f;
            v[0] = (_Float16)hs;               // Hs = Hxy+Hyx
            v[1] = (_Float16)0.0f;
            v[2] = (_Float16)hyy;              // Hyy
            v[3] = (_Float16)(1.0f/(tau*tau)); // D
            *(half4v*)&fl[flidx + 4] = v;
            if ((unsigned)(ry - 1) <= 1u)      // central rows only (no double count)
                ldacc += __logf(tau);          // -0.5*logdetD == +sum(log tau)
        }
    }
    __syncthreads();                           // xt dead; ys region live

    // ---- Y: y = A(x) rows i0-1..i0+2, one 4-px task per thread ----
    if (tid < 16){                             // zero col halos of ys
        int tl = tid >> 3, row = (tid >> 1) & 3, side = tid & 1;
        ys[(tl*4 + row)*268 + (side ? 260 : 3)] = 0.0f;
    }
    {
        int tl  = tid >> 8;
        int row = (tid >> 6) & 3;
        int cg  = tid & 63;
        int jc  = cg << 2;
        int gi  = i0 - 1 + row;
        float4 y4 = make_float4(0,0,0,0);
        if ((unsigned)gi < 256u){
            int bt  = (b << 3) + (tp << 1) + tl;
            int pix = (bt << 16) + (gi << 8) + jc;
            int rb  = pix - jc;
            float vc[6], vn[6], vs[6];
            row6(x, rb, jc, vc);
            if (gi < 255) row6(x, rb + 256, jc, vn); else zero6(vn);
            if (gi > 0)   row6(x, rb - 256, jc, vs); else zero6(vs);
            float k2[4], m1[4], m2[4], hx[4], hsv[4], hy[4], yv[4];
            #pragma unroll
            for (int p = 0; p < 4; ++p){
                half8 f8 = *(const half8*)&fl[(((((row << 1) + tl) << 8) + swz(jc + p)) << 3)];
                k2[p]=(float)f8[0]; m1[p]=(float)f8[1]; m2[p]=(float)f8[2];
                hx[p]=(float)f8[3]; hsv[p]=(float)f8[4]; hy[p]=(float)f8[6];
            }
            stencil4(k2, m1, m2, hx, hsv, hy, vc, vn, vs, yv);
            y4 = make_float4(yv[0], yv[1], yv[2], yv[3]);
        }
        *(float4*)&ys[(tl*4 + row)*268 + 4 + jc] = y4;
    }
    __syncthreads();

    // ---- Z: z = A(y) rows i0..i0+1; residual + D r^2 (256 threads) ----
    float local = 0.0f;
    if (tid < 256){
        int tl = tid >> 7;
        int zr = (tid >> 6) & 1;
        int cg = tid & 63;
        int jc = cg << 2;
        int gi = i0 + zr;
        int t  = (tp << 1) + tl;
        int pix = (((b << 3) + t) << 16) + (gi << 8) + jc;
        int yb  = (tl*4 + zr + 1)*268 + 4 + jc;

        float vc[6], vn[6], vs[6];
        {
            float4 c4 = *(const float4*)&ys[yb];
            vc[1]=c4.x; vc[2]=c4.y; vc[3]=c4.z; vc[4]=c4.w;
            vc[0]=ys[yb-1]; vc[5]=ys[yb+4];
            float4 n4 = *(const float4*)&ys[yb+268];
            vn[1]=n4.x; vn[2]=n4.y; vn[3]=n4.z; vn[4]=n4.w;
            vn[0]=ys[yb+268-1]; vn[5]=ys[yb+268+4];
            float4 s4 = *(const float4*)&ys[yb-268];
            vs[1]=s4.x; vs[2]=s4.y; vs[3]=s4.z; vs[4]=s4.w;
            vs[0]=ys[yb-268-1]; vs[5]=ys[yb-268+4];
        }
        float k2[4], m1[4], m2[4], hx[4], hsv[4], hy[4], dv[4], zv[4];
        #pragma unroll
        for (int p = 0; p < 4; ++p){
            half8 f8 = *(const half8*)&fl[((((((zr + 1) << 1) + tl) << 8) + swz(jc + p)) << 3)];
            k2[p]=(float)f8[0]; m1[p]=(float)f8[1]; m2[p]=(float)f8[2];
            hx[p]=(float)f8[3]; hsv[p]=(float)f8[4]; hy[p]=(float)f8[6];
            dv[p]=(float)f8[7];
        }
        stencil4(k2, m1, m2, hx, hsv, hy, vc, vn, vs, zv);

        float4 xc = *(const float4*)&x[pix];
        float4 xp = make_float4(0,0,0,0);
        if (t > 0) xp = *(const float4*)&x[pix - IMG];
        const float* xcp = (const float*)&xc;
        const float* xpp = (const float*)&xp;
        #pragma unroll
        for (int q = 0; q < 4; ++q){
            float r = xcp[q] + zv[q] - xpp[q];
            local += dv[q]*r*r;
        }
    }

    // ---- reduction: 0.5*sum(D r^2) + sum(log tau) ----
    red[tid] = 0.5f*local + ldacc;
    __syncthreads();
    for (int s = 256; s > 0; s >>= 1){
        if (tid < s) red[tid] += red[tid + s];
        __syncthreads();
    }
    if (tid == 0) atomicAdd(out, red[0]);
}

extern "C" void kernel_launch(void* const* d_in, const int* in_sizes, int n_in,
                              void* d_out, int out_size, void* d_ws, size_t ws_size,
                              hipStream_t stream)
{
    const float* x = (const float*)d_in[0];
    const float* w = (const float*)d_in[1];
    float* out = (float*)d_out;

    zero_out<<<1, 1, 0, stream>>>(out);
    fused_all<<<dim3(128, 16), 512, 0, stream>>>(x, w, out);
}

// Round 4
// 113.508 us; speedup vs baseline: 1.1700x; 1.1700x over previous
//
#include <hip/hip_runtime.h>

#define IMG 65536                  // H*W

typedef _Float16 half8  __attribute__((ext_vector_type(8)));
typedef _Float16 half4v __attribute__((ext_vector_type(4)));
typedef _Float16 half2v __attribute__((ext_vector_type(2)));
typedef float    floatx4 __attribute__((ext_vector_type(4)));

__device__ __forceinline__ float sigm(float x){ return 1.0f/(1.0f + __expf(-x)); }
__device__ __forceinline__ float tanh_fast(float x){
    float t = __expf(2.0f*x);
    return 1.0f - 2.0f/(t + 1.0f);
}
// XOR swizzle spreads 16B/px field accesses across banks
__device__ __forceinline__ int swz(int px){ return px ^ ((px >> 3) & 7); }

__global__ void zero_out(float* out){ out[0] = 0.0f; }

__device__ __forceinline__ void row6(const float* __restrict__ u, int rb, int j0, float v[6]){
    const float4 c4 = *(const float4*)&u[rb + j0];
    v[1] = c4.x; v[2] = c4.y; v[3] = c4.z; v[4] = c4.w;
    v[0] = (j0 > 0)   ? u[rb + j0 - 1] : 0.0f;
    v[5] = (j0 < 252) ? u[rb + j0 + 4] : 0.0f;
}
__device__ __forceinline__ void zero6(float v[6]){ v[0]=v[1]=v[2]=v[3]=v[4]=v[5]=0.0f; }

__device__ __forceinline__ void stencil4(const float k2[4], const float m1[4],
    const float m2[4], const float hx[4], const float hs[4], const float hy[4],
    const float vc[6], const float vn[6], const float vs[6], float rp[4])
{
    #pragma unroll
    for (int p = 0; p < 4; ++p){
        float hxx = hx[p], hyy = hy[p];
        rp[p] = (k2[p] + 2.0f*(hxx + hyy))*vc[p+1]
              + (0.5f*m1[p] - hxx)*vc[p+2]
              - (0.5f*m1[p] + hxx)*vc[p]
              + (0.5f*m2[p] - hyy)*vn[p+1]
              - (0.5f*m2[p] + hyy)*vs[p+1]
              - 0.25f*hs[p]*(vn[p+2] - vs[p+2] - vn[p] + vs[p]);
    }
}

// ---------------------------------------------------------------------------
// Fully fused, 8-row z-strips. Block = (b, t-pair, strip). 512 threads.
// LDS: xt [12 rows][258 cols][8ch] f16 (49536 B) -- aliased after conv by
//      ys [2t][10 rows][268] f32 (21440 B) + red (8 f32 @ 21440);
//      fl [10 rows x 2t][256 px][8ch] f16 (81920 B) at offset 49536.
// fl ch: 0 k2, 1 m1, 2 m2, 3 Hxx, 4 Hs, 5 Hyy, 6 D, 7 pad.
// ---------------------------------------------------------------------------
__global__ __launch_bounds__(512) void fused_all(
    const float* __restrict__ x, const float* __restrict__ w,
    float* __restrict__ out)
{
    __shared__ __align__(16) unsigned char smem[49536 + 81920];
    _Float16* xt  = (_Float16*)smem;
    _Float16* fl  = (_Float16*)(smem + 49536);
    float*    ys  = (float*)smem;                 // alias over dead xt
    float*    red = (float*)(smem + 21440);

    const int tid  = threadIdx.x;
    const int lane = tid & 63;
    const int wv   = tid >> 6;
    const int l16  = lane & 15;
    const int quad = lane >> 4;
    const int i0   = blockIdx.x << 3;             // z rows i0..i0+7
    const int b    = blockIdx.y >> 2;
    const int tp   = blockIdx.y & 3;              // t-pair {2tp, 2tp+1}

    // ---- stage x rows i0-2..i0+9, cols -1..256, 8ch f16 interleaved ----
    // lane layout: cp = tid&3 (channel pair, low bits -> contiguous LDS)
    {
        const int cp  = tid & 3;
        const int ccb = tid >> 2;                 // 0..127
        const int pl  = ((b << 3) + (cp << 1)) << 16;   // plane of ch 2cp
        #pragma unroll 2
        for (int rr = 0; rr < 12; ++rr){
            const int gi = i0 - 2 + rr;
            const bool rowok = (unsigned)gi < 256u;
            const int rowb = pl + (gi << 8);
            #pragma unroll
            for (int p = 0; p < 2; ++p){
                int cc = ccb + (p << 7);
                int gj = cc - 1;
                float v0 = 0.0f, v1 = 0.0f;
                if (rowok && (unsigned)gj < 256u){
                    v0 = x[rowb + gj];
                    v1 = x[rowb + gj + IMG];
                }
                half2v h; h[0] = (_Float16)v0; h[1] = (_Float16)v1;
                *(half2v*)&xt[(rr*258 + cc)*8 + (cp << 1)] = h;
            }
            if (tid < 8){
                int cc = 256 + (tid >> 2);        // 256,257
                int gj = cc - 1;
                float v0 = 0.0f, v1 = 0.0f;
                if (rowok && gj < 256){
                    v0 = x[rowb + gj];
                    v1 = x[rowb + gj + IMG];
                }
                half2v h; h[0] = (_Float16)v0; h[1] = (_Float16)v1;
                *(half2v*)&xt[(rr*258 + cc)*8 + (cp << 1)] = h;
            }
        }
    }

    // ---- weight A-frags: m = tl*8 + f -> oc = f*8 + 2tp + tl ----
    half8 afr[3];
    int boff[3];
    {
        int oc = ((l16 & 7) << 3) + (tp << 1) + (l16 >> 3);
        #pragma unroll
        for (int s = 0; s < 3; ++s){
            int tap = s*4 + quad;
            half8 a;
            if (tap < 9){
                #pragma unroll
                for (int j = 0; j < 8; ++j)
                    a[j] = (_Float16)w[(oc*8 + j)*9 + tap];
                int dh = tap/3, dw = tap - dh*3;
                boff[s] = (dh*258 + dw)*8;
            } else {
                #pragma unroll
                for (int j = 0; j < 8; ++j) a[j] = (_Float16)0.0f;
                boff[s] = 0;
            }
            afr[s] = a;
        }
    }
    __syncthreads();

    // ---- conv: 160 tiles (10 field rows x 16 colgroups), 20 per wave ----
    float ldacc = 0.0f;
    const int tl_c  = quad >> 1;                  // t within pair
    const int fhi   = quad & 1;                   // field group
    #pragma unroll 2
    for (int it = 0; it < 20; ++it){
        const int g  = it*8 + wv;
        const int ry = g >> 4;                    // field row: gi = i0-1+ry
        const int jb = ((g & 15) << 4) + l16;
        const int base = (ry*258 + jb)*8;
        floatx4 acc = {0,0,0,0};
        #pragma unroll
        for (int s = 0; s < 3; ++s){
            half8 bf = *(const half8*)&xt[base + boff[s]];
            acc = __builtin_amdgcn_mfma_f32_16x16x32_f16(afr[s], bf, acc, 0, 0, 0);
        }
        const int flidx = ((((ry << 1) + tl_c) << 8) + swz(jb)) << 3;
        half4v v;
        if (fhi == 0){                            // f0..3: k2, m1, m2, Hxx
            float s0 = 0.99f*sigm(acc[0]) + 0.01f;
            v[0] = (_Float16)(s0*s0);
            v[1] = (_Float16)acc[1];
            v[2] = (_Float16)acc[2];
            v[3] = (_Float16)(0.99f*sigm(acc[3]) + 0.01f);
            *(half4v*)&fl[flidx] = v;
        } else {                                  // f4..7: Hxy,Hyx,Hyy,tau
            float hs  = 0.1f*(tanh_fast(acc[0]) + tanh_fast(acc[1]));
            float hyy = 0.99f*sigm(acc[2]) + 0.01f;
            float tau = 9.9f*sigm(acc[3]) + 0.1f;
            v[0] = (_Float16)hs;
            v[1] = (_Float16)hyy;
            v[2] = (_Float16)(1.0f/(tau*tau));
            v[3] = (_Float16)0.0f;
            *(half4v*)&fl[flidx + 4] = v;
            if ((unsigned)(ry - 1) <= 7u)         // central rows: count once
                ldacc += __logf(tau);             // -0.5*logdetD == +sum log tau
        }
    }
    __syncthreads();                              // xt dead; ys live

    // ---- Y: y = A(x), 1280 tasks (2t x 10 rows x 64 colgroups) ----
    if (tid < 40){                                // zero ys col halos
        int r2 = tid >> 1, side = tid & 1;
        ys[r2*268 + (side ? 260 : 3)] = 0.0f;
    }
    #pragma unroll
    for (int p = 0; p < 3; ++p){
        if (p == 2 && tid >= 256) break;
        const int task = p*512 + tid;
        const int cg   = task & 63;
        const int rowt = task >> 6;               // 0..19
        const int tl   = (rowt >= 10) ? 1 : 0;
        const int ry   = rowt - (tl ? 10 : 0);
        const int jc   = cg << 2;
        const int gi   = i0 - 1 + ry;
        float4 y4 = make_float4(0,0,0,0);
        if ((unsigned)gi < 256u){
            const int bt  = (b << 3) + (tp << 1) + tl;
            const int pix = (bt << 16) + (gi << 8) + jc;
            const int rb  = pix - jc;
            float vc[6], vn[6], vs[6];
            row6(x, rb, jc, vc);
            if (gi < 255) row6(x, rb + 256, jc, vn); else zero6(vn);
            if (gi > 0)   row6(x, rb - 256, jc, vs); else zero6(vs);
            float k2[4], m1[4], m2[4], hx[4], hsv[4], hy[4], yv[4];
            const int frow = (((ry << 1) + tl) << 8);
            #pragma unroll
            for (int q = 0; q < 4; ++q){
                half8 f8 = *(const half8*)&fl[(frow + swz(jc + q)) << 3];
                k2[q]=(float)f8[0]; m1[q]=(float)f8[1]; m2[q]=(float)f8[2];
                hx[q]=(float)f8[3]; hsv[q]=(float)f8[4]; hy[q]=(float)f8[5];
            }
            stencil4(k2, m1, m2, hx, hsv, hy, vc, vn, vs, yv);
            y4 = make_float4(yv[0], yv[1], yv[2], yv[3]);
        }
        *(float4*)&ys[(tl*10 + ry)*268 + 4 + jc] = y4;
    }
    __syncthreads();

    // ---- Z: z = A(y), 1024 tasks (2t x 8 rows x 64 cg); residual ----
    float local = 0.0f;
    #pragma unroll
    for (int p = 0; p < 2; ++p){
        const int task = p*512 + tid;
        const int cg   = task & 63;
        const int rowz = task >> 6;               // 0..15
        const int tl   = rowz >> 3;
        const int zr   = rowz & 7;
        const int jc   = cg << 2;
        const int gi   = i0 + zr;
        const int t    = (tp << 1) + tl;
        const int pix  = (((b << 3) + t) << 16) + (gi << 8) + jc;
        const int yb   = (tl*10 + zr + 1)*268 + 4 + jc;

        float vc[6], vn[6], vs[6];
        {
            float4 c4 = *(const float4*)&ys[yb];
            vc[1]=c4.x; vc[2]=c4.y; vc[3]=c4.z; vc[4]=c4.w;
            vc[0]=ys[yb-1]; vc[5]=ys[yb+4];
            float4 n4 = *(const float4*)&ys[yb+268];
            vn[1]=n4.x; vn[2]=n4.y; vn[3]=n4.z; vn[4]=n4.w;
            vn[0]=ys[yb+268-1]; vn[5]=ys[yb+268+4];
            float4 s4 = *(const float4*)&ys[yb-268];
            vs[1]=s4.x; vs[2]=s4.y; vs[3]=s4.z; vs[4]=s4.w;
            vs[0]=ys[yb-268-1]; vs[5]=ys[yb-268+4];
        }
        float k2[4], m1[4], m2[4], hx[4], hsv[4], hy[4], dv[4], zv[4];
        const int frow = ((((zr + 1) << 1) + tl) << 8);
        #pragma unroll
        for (int q = 0; q < 4; ++q){
            half8 f8 = *(const half8*)&fl[(frow + swz(jc + q)) << 3];
            k2[q]=(float)f8[0]; m1[q]=(float)f8[1]; m2[q]=(float)f8[2];
            hx[q]=(float)f8[3]; hsv[q]=(float)f8[4]; hy[q]=(float)f8[5];
            dv[q]=(float)f8[6];
        }
        stencil4(k2, m1, m2, hx, hsv, hy, vc, vn, vs, zv);

        float4 xc = *(const float4*)&x[pix];
        float4 xp = make_float4(0,0,0,0);
        if (t > 0) xp = *(const float4*)&x[pix - IMG];
        const float* xcp = (const float*)&xc;
        const float* xpp = (const float*)&xp;
        #pragma unroll
        for (int q = 0; q < 4; ++q){
            float r = xcp[q] + zv[q] - xpp[q];
            local += dv[q]*r*r;
        }
    }

    // ---- reduction: 0.5*sum(D r^2) + sum(log tau) ----
    float v = 0.5f*local + ldacc;
    #pragma unroll
    for (int off = 1; off < 64; off <<= 1)
        v += __shfl_xor(v, off, 64);
    __syncthreads();                              // ys reads done before red write
    if (lane == 0) red[wv] = v;
    __syncthreads();
    if (tid == 0){
        float s = 0.0f;
        #pragma unroll
        for (int k = 0; k < 8; ++k) s += red[k];
        atomicAdd(out, s);
    }
}

extern "C" void kernel_launch(void* const* d_in, const int* in_sizes, int n_in,
                              void* d_out, int out_size, void* d_ws, size_t ws_size,
                              hipStream_t stream)
{
    const float* x = (const float*)d_in[0];
    const float* w = (const float*)d_in[1];
    float* out = (float*)d_out;

    zero_out<<<1, 1, 0, stream>>>(out);
    fused_all<<<dim3(32, 16), 512, 0, stream>>>(x, w, out);
}